// Round 3
// baseline (256.989 us; speedup 1.0000x reference)
//
#include <hip/hip_runtime.h>
#include <hip/hip_fp16.h>
#include <math.h>

typedef _Float16 f16;
typedef _Float16 f16x8 __attribute__((ext_vector_type(8)));
typedef _Float16 f16x4 __attribute__((ext_vector_type(4)));
typedef float f32x4 __attribute__((ext_vector_type(4)));

namespace {
constexpr int kB = 32, kD = 512, kN = 1024, kF = 256;
constexpr float kScale = 0.04419417382415922f;   // 1/sqrt(512)
constexpr float kLogMarg = -6.931471805599453f;  // -log(1024)
constexpr float kMarg = 1.f / 1024.f;            // 1/n
constexpr float kPScale = 16384.f;               // 2^14: lift exp into f16 range
constexpr float kPInv = 1.f / 16384.f;
}

// global -> LDS direct DMA, 16B per lane. LDS dest is wave-uniform base +
// lane*16 (hardware); global src is per-lane.
__device__ __forceinline__ void gload16(const void* g, void* l) {
  __builtin_amdgcn_global_load_lds(
      (const __attribute__((address_space(1))) void*)g,
      (__attribute__((address_space(3))) void*)l, 16, 0, 0);
}

// ---- K1: val = x[b,c,i] + pos(c,i); emit xfT[lb,c,i] and xf[lb,i,c] (f16) --
__global__ __launch_bounds__(256) void k_prep(
    const float* __restrict__ x, const float* __restrict__ re,
    const float* __restrict__ ce, f16* __restrict__ xf,
    f16* __restrict__ xfT, int b0) {
  __shared__ f16 T[64][68];
  const int lb = blockIdx.z;
  const int i0 = blockIdx.x * 64, c0 = blockIdx.y * 64;
  const int t = threadIdx.x;
  const int il = (t & 15) * 4;  // 0..60
  const int cl = t >> 4;        // 0..15
  const size_t xbase = ((size_t)(b0 + lb) * kD) * kN;
#pragma unroll
  for (int p = 0; p < 4; p++) {
    const int c = c0 + cl + 16 * p;
    const int i = i0 + il;
    const float4 xv = *(const float4*)(x + xbase + (size_t)c * kN + i);
    float4 pv;
    if (c < kF) {  // wave-uniform per block (c0 multiple of 64)
      pv.x = ce[((i + 0) & 31) * kF + c];
      pv.y = ce[((i + 1) & 31) * kF + c];
      pv.z = ce[((i + 2) & 31) * kF + c];
      pv.w = ce[((i + 3) & 31) * kF + c];
    } else {
      const float r = re[(i >> 5) * kF + (c - kF)];
      pv.x = r; pv.y = r; pv.z = r; pv.w = r;
    }
    const f16 h0 = (f16)(xv.x + pv.x), h1 = (f16)(xv.y + pv.y);
    const f16 h2 = (f16)(xv.z + pv.z), h3 = (f16)(xv.w + pv.w);
    f16* dT = xfT + ((size_t)lb * kD + c) * kN + i;
    *(f16x4*)dT = (f16x4){h0, h1, h2, h3};
    T[cl + 16 * p][il + 0] = h0; T[cl + 16 * p][il + 1] = h1;
    T[cl + 16 * p][il + 2] = h2; T[cl + 16 * p][il + 3] = h3;
  }
  __syncthreads();
#pragma unroll
  for (int p = 0; p < 4; p++) {
    const int ir = cl + 16 * p;  // local i
    const int cc = il;           // local c
    const f16 h0 = T[cc + 0][ir], h1 = T[cc + 1][ir];
    const f16 h2 = T[cc + 2][ir], h3 = T[cc + 3][ir];
    f16* dF = xf + ((size_t)lb * kN + i0 + ir) * kD + c0 + cc;
    *(f16x4*)dF = (f16x4){h0, h1, h2, h3};
  }
}

// ---- K2: S16 = f16(kScale * xf @ xf^T) -------------------------------------
// 256x256 tile, 8 waves (2M x 4N), per-wave 128x64 output, BK=64, 2-deep
// double-buffered (128 KB LDS, 1 block/CU). gload_lds(16B) + T2 XOR swizzle
// (pre-swizzled global source, swizzled ds_read). One barrier per K-step.
// T1 XCD-chunked block swizzle.
__global__ __launch_bounds__(512) void k_gemm_s(
    const f16* __restrict__ xf, f16* __restrict__ S16,
    float* __restrict__ rp) {
  __shared__ char sm[131072];  // buf0: A[0,32K) B[32K,64K); buf1 at +64K
  const int nwg = (int)(gridDim.x * gridDim.y * gridDim.z);  // 16*g, %8==0
  const int lin = (int)(blockIdx.x +
                        gridDim.x * (blockIdx.y + gridDim.y * blockIdx.z));
  const int wid = (lin & 7) * (nwg >> 3) + (lin >> 3);
  const int bx = wid & 3, by = (wid >> 2) & 3, bz = wid >> 4;

  const int lb = bz;
  const int i0 = by * 256, j0 = bx * 256;
  const char* base = (const char*)(xf + (size_t)lb * kN * kD);
  const int t = threadIdx.x;  // 0..511
  const int w = t >> 6, lane = t & 63;
  const int wm = w >> 2, wn = w & 3;            // wave grid 2M x 4N
  const int m_off = wm * 128, n_off = wn * 64;  // per-wave 128x64
  const int quad = lane >> 4, l15 = lane & 15;
  const int swz = (l15 & 7) << 4;

  // staging: A/B tiles 32 KB each = 4 chunks x (512 thr x 16 B)
  int srcA[4], srcB[4], ldsw[4];
#pragma unroll
  for (int p = 0; p < 4; p++) {
    const int off = p * 8192 + t * 16;
    const int r = off >> 7;                       // tile row 0..255
    const int cb = (off & 127) ^ ((r & 7) << 4);  // inverse-swizzled src col
    srcA[p] = (i0 + r) * (kD * 2) + cb;           // row stride 1024 B
    srcB[p] = (j0 + r) * (kD * 2) + cb;
    ldsw[p] = p * 8192 + w * 1024;                // wave-uniform LDS base
  }

  f32x4 acc[8][4];
#pragma unroll
  for (int a = 0; a < 8; a++)
#pragma unroll
    for (int b = 0; b < 4; b++) acc[a][b] = (f32x4){0.f, 0.f, 0.f, 0.f};

  // prologue: stage K-tile 0 into buf0
#pragma unroll
  for (int p = 0; p < 4; p++) gload16(base + srcA[p], sm + ldsw[p]);
#pragma unroll
  for (int p = 0; p < 4; p++) gload16(base + srcB[p], sm + 32768 + ldsw[p]);
  __syncthreads();

#pragma unroll
  for (int tt = 0; tt < 8; tt++) {  // 8 K-tiles of 64 f16 (128 B)
    const int cur = tt & 1, nxt = cur ^ 1;
    if (tt + 1 < 8) {  // issue next tile's loads FIRST (overlap with compute)
      const int k0b = (tt + 1) * 128;
#pragma unroll
      for (int p = 0; p < 4; p++)
        gload16(base + srcA[p] + k0b, sm + (nxt << 16) + ldsw[p]);
#pragma unroll
      for (int p = 0; p < 4; p++)
        gload16(base + srcB[p] + k0b, sm + (nxt << 16) + 32768 + ldsw[p]);
    }
    const char* bA = sm + (cur << 16);
    const char* bB = bA + 32768;
#pragma unroll
    for (int kk = 0; kk < 2; kk++) {
      f16x8 af[8], bf[4];
#pragma unroll
      for (int q = 0; q < 8; q++)
        af[q] = *(const f16x8*)(bA + (m_off + 16 * q + l15) * 128 +
                                ((kk * 64 + quad * 16) ^ swz));
#pragma unroll
      for (int q = 0; q < 4; q++)
        bf[q] = *(const f16x8*)(bB + (n_off + 16 * q + l15) * 128 +
                                ((kk * 64 + quad * 16) ^ swz));
#pragma unroll
      for (int qa = 0; qa < 8; qa++)
#pragma unroll
        for (int qb = 0; qb < 4; qb++)
          acc[qa][qb] = __builtin_amdgcn_mfma_f32_16x16x32_f16(
              af[qa], bf[qb], acc[qa][qb], 0, 0, 0);
    }
    __syncthreads();  // next tile staged; cur safe to overwrite next iter
  }

  f16* Sb = S16 + (size_t)lb * kN * kN;
  const int jt = bx * 4 + wn;  // 0..15: 64-wide j segment index
  float* rpb = rp + ((size_t)lb * 16 + jt) * kN + i0 + m_off;
#pragma unroll
  for (int qa = 0; qa < 8; qa++) {
    const int i = i0 + m_off + 16 * qa + quad * 4;
    float rs[4] = {0.f, 0.f, 0.f, 0.f};
#pragma unroll
    for (int qb = 0; qb < 4; qb++) {
      const int j = j0 + n_off + 16 * qb + l15;
#pragma unroll
      for (int r = 0; r < 4; r++) {
        const f16 h = (f16)(acc[qa][qb][r] * kScale);
        Sb[(size_t)(i + r) * kN + j] = h;
        rs[r] += __expf((float)h);
      }
    }
#pragma unroll
    for (int r = 0; r < 4; r++) {
      float s = rs[r];
      s += __shfl_xor(s, 1);
      s += __shfl_xor(s, 2);
      s += __shfl_xor(s, 4);
      s += __shfl_xor(s, 8);
      if (l15 == 0) rpb[16 * qa + 4 * quad + r] = s;
    }
  }
}

// ---- K3: u[lb,i] = -log(n) - log(sum of 16 row partials) -------------------
__global__ __launch_bounds__(256) void k_u(
    const float* __restrict__ rp, float* __restrict__ u) {
  const int lb = blockIdx.y;
  const int i = blockIdx.x * 256 + threadIdx.x;
  const float* r = rp + (size_t)lb * 16 * kN + i;
  float s = 0.f;
#pragma unroll
  for (int t = 0; t < 16; t++) s += r[(size_t)t * kN];
  u[lb * kN + i] = kLogMarg - __logf(s);
}

// ---- K4: E16 = f16(2^14*exp(S16+u_i)); column partial sums of exp ----------
// (replaces old k_cs and absorbs k_pt's exp-pass; ev is folded into gemm_o's
// A staging instead of into this tensor.)
__global__ __launch_bounds__(256) void k_cs(
    const f16* __restrict__ S16, const float* __restrict__ u,
    float* __restrict__ cp, f16* __restrict__ E16) {
  const int lb = blockIdx.z;
  const int seg = blockIdx.y;
  const int j = blockIdx.x * 256 + threadIdx.x;
  const f16* Sb = S16 + (size_t)lb * kN * kN + j;
  f16* Eb = E16 + (size_t)lb * kN * kN + j;
  const float* ub = u + lb * kN + seg * 64;
  const size_t rbase = (size_t)(seg * 64) * kN;
  float s = 0.f;
#pragma unroll 4
  for (int r = 0; r < 64; r++) {
    const float eS = __expf((float)Sb[rbase + (size_t)r * kN] + ub[r]);
    s += eS;
    Eb[rbase + (size_t)r * kN] = (f16)(eS * kPScale);
  }
  cp[((size_t)lb * 16 + seg) * kN + j] = s;
}

// ---- K5: ev[lb,j] = exp(v_j) = (1/n) / colsum_j ----------------------------
__global__ __launch_bounds__(256) void k_v(
    const float* __restrict__ cp, float* __restrict__ ev) {
  const int lb = blockIdx.y;
  const int j = blockIdx.x * 256 + threadIdx.x;
  const float* c = cp + (size_t)lb * 16 * kN + j;
  float s = 0.f;
#pragma unroll
  for (int r = 0; r < 16; r++) s += c[(size_t)r * kN];
  ev[lb * kN + j] = kMarg / s;
}

// ---- K6: out[b,c,i] = (1/2^14) * sum_j (xfT[c,j]*ev_j) * E16[i,j] ----------
// 256x256 tile like k_gemm_s. B (E16) via gload_lds + pre-swizzled source.
// A = xfT*ev is REG-STAGED: linear global f16x8 load (issued before compute,
// latency hides under MFMA), ev multiply, swizzled ds_write into next buffer.
__global__ __launch_bounds__(512) void k_gemm_o(
    const f16* __restrict__ xfT, const f16* __restrict__ E16,
    const float* __restrict__ ev, float* __restrict__ out, int b0) {
  __shared__ char sm[131072];
  const int nwg = (int)(gridDim.x * gridDim.y * gridDim.z);  // 8*g, %8==0
  const int lin = (int)(blockIdx.x +
                        gridDim.x * (blockIdx.y + gridDim.y * blockIdx.z));
  const int wid = (lin & 7) * (nwg >> 3) + (lin >> 3);
  const int bx = wid & 3, by = (wid >> 2) & 1, bz = wid >> 3;

  const int lb = bz;
  const int i0 = bx * 256, c0 = by * 256;
  const char* Ab = (const char*)(xfT + (size_t)lb * kD * kN);  // rows c
  const char* Bb = (const char*)(E16 + (size_t)lb * kN * kN);  // rows i
  const float* evb = ev + (size_t)lb * kN;
  const int t = threadIdx.x;
  const int w = t >> 6, lane = t & 63;
  const int wm = w >> 2, wn = w & 3;
  const int m_off = wm * 128, n_off = wn * 64;
  const int quad = lane >> 4, l15 = lane & 15;
  const int swz = (l15 & 7) << 4;

  int srcAlin[4], dstA[4], srcB[4], ldsw[4], evcol[4];
#pragma unroll
  for (int p = 0; p < 4; p++) {
    const int off = p * 8192 + t * 16;
    const int r = off >> 7;        // tile row 0..255
    const int cbl = off & 127;     // linear col byte
    const int cb = cbl ^ ((r & 7) << 4);
    srcAlin[p] = (c0 + r) * (kN * 2) + cbl;  // LINEAR source (reg-staged)
    dstA[p] = r * 128 + cb;                  // swizzled LDS byte (A region)
    srcB[p] = (i0 + r) * (kN * 2) + cb;      // pre-swizzled (gload_lds)
    ldsw[p] = p * 8192 + w * 1024;
    evcol[p] = cbl >> 1;                     // f16 col 0..56, %8==0
  }

  f32x4 acc[8][4];
#pragma unroll
  for (int a = 0; a < 8; a++)
#pragma unroll
    for (int b = 0; b < 4; b++) acc[a][b] = (f32x4){0.f, 0.f, 0.f, 0.f};

  f16x8 al[4];
  float4 e0[4], e1[4];
  // prologue: stage K-tile 0 into buf0
#pragma unroll
  for (int p = 0; p < 4; p++) {
    al[p] = *(const f16x8*)(Ab + srcAlin[p]);
    e0[p] = *(const float4*)(evb + evcol[p]);
    e1[p] = *(const float4*)(evb + evcol[p] + 4);
  }
#pragma unroll
  for (int p = 0; p < 4; p++) gload16(Bb + srcB[p], sm + 32768 + ldsw[p]);
#pragma unroll
  for (int p = 0; p < 4; p++) {
    f16x8 pr;
    pr[0] = (f16)((float)al[p][0] * e0[p].x);
    pr[1] = (f16)((float)al[p][1] * e0[p].y);
    pr[2] = (f16)((float)al[p][2] * e0[p].z);
    pr[3] = (f16)((float)al[p][3] * e0[p].w);
    pr[4] = (f16)((float)al[p][4] * e1[p].x);
    pr[5] = (f16)((float)al[p][5] * e1[p].y);
    pr[6] = (f16)((float)al[p][6] * e1[p].z);
    pr[7] = (f16)((float)al[p][7] * e1[p].w);
    *(f16x8*)(sm + dstA[p]) = pr;
  }
  __syncthreads();

#pragma unroll
  for (int tt = 0; tt < 16; tt++) {  // 16 K-tiles of 64 f16
    const int cur = tt & 1, nxt = cur ^ 1;
    const bool pf = (tt + 1 < 16);
    if (pf) {  // issue next-tile A reg-loads + B gload_lds FIRST
      const int k0b = (tt + 1) * 128;
      const int k0f = (tt + 1) * 64;
#pragma unroll
      for (int p = 0; p < 4; p++) {
        al[p] = *(const f16x8*)(Ab + srcAlin[p] + k0b);
        e0[p] = *(const float4*)(evb + k0f + evcol[p]);
        e1[p] = *(const float4*)(evb + k0f + evcol[p] + 4);
      }
#pragma unroll
      for (int p = 0; p < 4; p++)
        gload16(Bb + srcB[p] + k0b, sm + (nxt << 16) + 32768 + ldsw[p]);
    }
    const char* bA = sm + (cur << 16);
    const char* bB = bA + 32768;
#pragma unroll
    for (int kk = 0; kk < 2; kk++) {
      f16x8 af[8], bf[4];
#pragma unroll
      for (int q = 0; q < 8; q++)
        af[q] = *(const f16x8*)(bA + (m_off + 16 * q + l15) * 128 +
                                ((kk * 64 + quad * 16) ^ swz));
#pragma unroll
      for (int q = 0; q < 4; q++)
        bf[q] = *(const f16x8*)(bB + (n_off + 16 * q + l15) * 128 +
                                ((kk * 64 + quad * 16) ^ swz));
#pragma unroll
      for (int qa = 0; qa < 8; qa++)
#pragma unroll
        for (int qb = 0; qb < 4; qb++)
          acc[qa][qb] = __builtin_amdgcn_mfma_f32_16x16x32_f16(
              af[qa], bf[qb], acc[qa][qb], 0, 0, 0);
    }
    if (pf) {  // A-regs ready by now (latency hidden); write into nxt
#pragma unroll
      for (int p = 0; p < 4; p++) {
        f16x8 pr;
        pr[0] = (f16)((float)al[p][0] * e0[p].x);
        pr[1] = (f16)((float)al[p][1] * e0[p].y);
        pr[2] = (f16)((float)al[p][2] * e0[p].z);
        pr[3] = (f16)((float)al[p][3] * e0[p].w);
        pr[4] = (f16)((float)al[p][4] * e1[p].x);
        pr[5] = (f16)((float)al[p][5] * e1[p].y);
        pr[6] = (f16)((float)al[p][6] * e1[p].z);
        pr[7] = (f16)((float)al[p][7] * e1[p].w);
        *(f16x8*)(sm + (nxt << 16) + dstA[p]) = pr;
      }
    }
    __syncthreads();
  }

  float* ob = out + ((size_t)(b0 + lb) * kD) * kN;
#pragma unroll
  for (int qa = 0; qa < 8; qa++) {
    const int c = c0 + m_off + 16 * qa + quad * 4;
#pragma unroll
    for (int qb = 0; qb < 4; qb++) {
      const int i = i0 + n_off + 16 * qb + l15;
#pragma unroll
      for (int r = 0; r < 4; r++)
        ob[(size_t)(c + r) * kN + i] = acc[qa][qb][r] * kPInv;
    }
  }
}

extern "C" void kernel_launch(void* const* d_in, const int* in_sizes, int n_in,
                              void* d_out, int out_size, void* d_ws, size_t ws_size,
                              hipStream_t stream) {
  const float* x = (const float*)d_in[0];
  const float* re = (const float*)d_in[1];
  const float* ce = (const float*)d_in[2];
  float* out = (float*)d_out;

  // ws per batch: S16 2MB + xf 1MB + xfT 1MB + E16 2MB + u 4KB + ev 4KB
  //             + rp 64KB + cp 64KB = ~6.13 MB. ws=256MiB -> G=32, ONE chunk.
  char* wsb = (char*)d_ws;
  const size_t perb = 2097152ull + 1048576 + 1048576 + 2097152 +
                      4096 + 4096 + 65536 + 65536;
  int G = (int)(ws_size / perb);
  if (G >= 32) G = 32;
  else if (G >= 16) G = 16;
  else if (G >= 8) G = 8;
  else if (G >= 4) G = 4;
  else if (G < 1) G = 1;
  f16* S16 = (f16*)wsb;
  f16* xf = (f16*)(wsb + (size_t)G * 2097152);
  f16* xfT = (f16*)((char*)xf + (size_t)G * 1048576);
  f16* E16 = (f16*)((char*)xfT + (size_t)G * 1048576);
  float* u = (float*)((char*)E16 + (size_t)G * 2097152);
  float* ev = u + (size_t)G * kN;
  float* rp = ev + (size_t)G * kN;            // [G][16][kN]
  float* cp = rp + (size_t)G * 16 * kN;       // [G][16][kN]

  for (int b0 = 0; b0 < kB; b0 += G) {
    const int g = (kB - b0 < G) ? (kB - b0) : G;
    k_prep<<<dim3(16, 8, g), 256, 0, stream>>>(x, re, ce, xf, xfT, b0);
    k_gemm_s<<<dim3(4, 4, g), 512, 0, stream>>>(xf, S16, rp);
    k_u<<<dim3(4, g), 256, 0, stream>>>(rp, u);
    k_cs<<<dim3(4, 16, g), 256, 0, stream>>>(S16, u, cp, E16);
    k_v<<<dim3(4, g), 256, 0, stream>>>(cp, ev);
    k_gemm_o<<<dim3(4, 2, g), 512, 0, stream>>>(xfT, E16, ev, out, b0);
  }
}

// Round 4
// 245.440 us; speedup vs baseline: 1.0471x; 1.0471x over previous
//
#include <hip/hip_runtime.h>
#include <hip/hip_fp16.h>
#include <math.h>

typedef _Float16 f16;
typedef _Float16 f16x8 __attribute__((ext_vector_type(8)));
typedef _Float16 f16x4 __attribute__((ext_vector_type(4)));
typedef float f32x4 __attribute__((ext_vector_type(4)));

namespace {
constexpr int kB = 32, kD = 512, kN = 1024, kF = 256;
constexpr float kScale = 0.04419417382415922f;   // 1/sqrt(512)
constexpr float kLogMarg = -6.931471805599453f;  // -log(1024)
constexpr float kMarg = 1.f / 1024.f;            // 1/n
constexpr float kPScale = 16384.f;               // 2^14: lift exp into f16 range
constexpr float kPInv = 1.f / 16384.f;
}

// global -> LDS direct DMA, 16B per lane. LDS dest is wave-uniform base +
// lane*16 (hardware); global src is per-lane.
__device__ __forceinline__ void gload16(const void* g, void* l) {
  __builtin_amdgcn_global_load_lds(
      (const __attribute__((address_space(1))) void*)g,
      (__attribute__((address_space(3))) void*)l, 16, 0, 0);
}

// ---- K1: val = x[b,c,i] + pos(c,i); emit xfT[lb,c,i] and xf[lb,i,c] (f16) --
__global__ __launch_bounds__(256) void k_prep(
    const float* __restrict__ x, const float* __restrict__ re,
    const float* __restrict__ ce, f16* __restrict__ xf,
    f16* __restrict__ xfT, int b0) {
  __shared__ f16 T[64][68];
  const int lb = blockIdx.z;
  const int i0 = blockIdx.x * 64, c0 = blockIdx.y * 64;
  const int t = threadIdx.x;
  const int il = (t & 15) * 4;  // 0..60
  const int cl = t >> 4;        // 0..15
  const size_t xbase = ((size_t)(b0 + lb) * kD) * kN;
#pragma unroll
  for (int p = 0; p < 4; p++) {
    const int c = c0 + cl + 16 * p;
    const int i = i0 + il;
    const float4 xv = *(const float4*)(x + xbase + (size_t)c * kN + i);
    float4 pv;
    if (c < kF) {  // wave-uniform per block (c0 multiple of 64)
      pv.x = ce[((i + 0) & 31) * kF + c];
      pv.y = ce[((i + 1) & 31) * kF + c];
      pv.z = ce[((i + 2) & 31) * kF + c];
      pv.w = ce[((i + 3) & 31) * kF + c];
    } else {
      const float r = re[(i >> 5) * kF + (c - kF)];
      pv.x = r; pv.y = r; pv.z = r; pv.w = r;
    }
    const f16 h0 = (f16)(xv.x + pv.x), h1 = (f16)(xv.y + pv.y);
    const f16 h2 = (f16)(xv.z + pv.z), h3 = (f16)(xv.w + pv.w);
    f16* dT = xfT + ((size_t)lb * kD + c) * kN + i;
    *(f16x4*)dT = (f16x4){h0, h1, h2, h3};
    T[cl + 16 * p][il + 0] = h0; T[cl + 16 * p][il + 1] = h1;
    T[cl + 16 * p][il + 2] = h2; T[cl + 16 * p][il + 3] = h3;
  }
  __syncthreads();
#pragma unroll
  for (int p = 0; p < 4; p++) {
    const int ir = cl + 16 * p;  // local i
    const int cc = il;           // local c
    const f16 h0 = T[cc + 0][ir], h1 = T[cc + 1][ir];
    const f16 h2 = T[cc + 2][ir], h3 = T[cc + 3][ir];
    f16* dF = xf + ((size_t)lb * kN + i0 + ir) * kD + c0 + cc;
    *(f16x4*)dF = (f16x4){h0, h1, h2, h3};
  }
}

// ---- K2: S16 = f16(kScale * xf @ xf^T) -------------------------------------
// 256x256 tile, 8 waves (2Mx4N), per-wave 128x64, BK=64, 2-deep dbuf.
// PHASE-SPLIT COUNTED-VMCNT schedule (T3+T4+T5): 4 phases per K-tile; phase q
// stages chunk q of the NEXT tile (2 gload_lds), reads a register subtile,
// barrier, setprio(1), 16 MFMA, setprio(0). One counted s_waitcnt vmcnt(2)
// per K-tile (never 0 in main loop); raw s_barrier (no __syncthreads drain).
// Hazards: read-validity = per-wave vmcnt(2) + entry barrier; WAR on the
// overwritten buffer = end-of-iter barrier (each wave's ds_reads are consumed
// by its MFMA before it can pass it). T2 swizzle + T1 XCD swizzle kept.
__global__ __launch_bounds__(512) void k_gemm_s(
    const f16* __restrict__ xf, f16* __restrict__ S16,
    float* __restrict__ rp) {
  __shared__ char sm[131072];  // buf d at d<<16: A[0,32K) B[32K,64K)
  const int nwg = (int)(gridDim.x * gridDim.y * gridDim.z);  // 16*g, %8==0
  const int lin = (int)(blockIdx.x +
                        gridDim.x * (blockIdx.y + gridDim.y * blockIdx.z));
  const int wid = (lin & 7) * (nwg >> 3) + (lin >> 3);
  const int bx = wid & 3, by = (wid >> 2) & 3, bz = wid >> 4;

  const int lb = bz;
  const int i0 = by * 256, j0 = bx * 256;
  const char* base = (const char*)(xf + (size_t)lb * kN * kD);
  const int t = threadIdx.x;  // 0..511
  const int w = t >> 6, lane = t & 63;
  const int wm = w >> 2, wn = w & 3;            // wave grid 2M x 4N
  const int m_off = wm * 128, n_off = wn * 64;  // per-wave 128x64
  const int quad = lane >> 4, l15 = lane & 15;
  const int swz = (l15 & 7) << 4;

  // staging: A/B tiles 32 KB each = 4 chunks x (512 thr x 16 B)
  int srcA[4], srcB[4], ldsw[4];
#pragma unroll
  for (int p = 0; p < 4; p++) {
    const int off = p * 8192 + t * 16;
    const int r = off >> 7;                       // tile row 0..255
    const int cb = (off & 127) ^ ((r & 7) << 4);  // inverse-swizzled src col
    srcA[p] = (i0 + r) * (kD * 2) + cb;           // row stride 1024 B
    srcB[p] = (j0 + r) * (kD * 2) + cb;
    ldsw[p] = p * 8192 + w * 1024;                // wave-uniform LDS base
  }

  // prologue: stage K-tile 0 into buf0 ASAP (cover latency with acc init)
#pragma unroll
  for (int p = 0; p < 4; p++) gload16(base + srcA[p], sm + ldsw[p]);
#pragma unroll
  for (int p = 0; p < 4; p++) gload16(base + srcB[p], sm + 32768 + ldsw[p]);

  f32x4 acc[8][4];
#pragma unroll
  for (int a = 0; a < 8; a++)
#pragma unroll
    for (int b = 0; b < 4; b++) acc[a][b] = (f32x4){0.f, 0.f, 0.f, 0.f};

#pragma unroll
  for (int tt = 0; tt < 8; tt++) {
    const int cur = tt & 1, nxt = cur ^ 1;
    const char* rA = sm + (cur << 16);
    const char* rB = rA + 32768;
    char* wA = sm + (nxt << 16);
    char* wB = wA + 32768;
    const int k0b = (tt + 1) * 128;
    f16x8 bf[4][2];
#pragma unroll
    for (int q = 0; q < 4; q++) {
      if (q == 0) {
        if (tt + 1 < 8) {  // issue 2 newest loads, then counted wait
          gload16(base + srcA[0] + k0b, wA + ldsw[0]);
          gload16(base + srcB[0] + k0b, wB + ldsw[0]);
          asm volatile("s_waitcnt vmcnt(2)" ::: "memory");
        } else {
          asm volatile("s_waitcnt vmcnt(0)" ::: "memory");
        }
        __builtin_amdgcn_s_barrier();  // tile tt fully staged for all waves
#pragma unroll
        for (int qb = 0; qb < 4; qb++)
#pragma unroll
          for (int kk = 0; kk < 2; kk++)
            bf[qb][kk] = *(const f16x8*)(rB + (n_off + 16 * qb + l15) * 128 +
                                         ((kk * 64 + quad * 16) ^ swz));
      } else {
        if (tt + 1 < 8) {
          gload16(base + srcA[q] + k0b, wA + ldsw[q]);
          gload16(base + srcB[q] + k0b, wB + ldsw[q]);
        }
      }
      f16x8 af[2][2];
#pragma unroll
      for (int pa = 0; pa < 2; pa++)
#pragma unroll
        for (int kk = 0; kk < 2; kk++)
          af[pa][kk] = *(const f16x8*)(rA + (m_off + 16 * (2 * q + pa) + l15) * 128 +
                                       ((kk * 64 + quad * 16) ^ swz));
      __builtin_amdgcn_s_barrier();  // cluster: reads issued, MFMA next
      __builtin_amdgcn_s_setprio(1);
#pragma unroll
      for (int pa = 0; pa < 2; pa++)
#pragma unroll
        for (int qb = 0; qb < 4; qb++)
#pragma unroll
          for (int kk = 0; kk < 2; kk++)
            acc[2 * q + pa][qb] = __builtin_amdgcn_mfma_f32_16x16x32_f16(
                af[pa][kk], bf[qb][kk], acc[2 * q + pa][qb], 0, 0, 0);
      __builtin_amdgcn_s_setprio(0);
    }
    __builtin_amdgcn_s_barrier();  // end-of-iter: WAR fence for buf overwrite
  }

  f16* Sb = S16 + (size_t)lb * kN * kN;
  const int jt = bx * 4 + wn;  // 0..15: 64-wide j segment index
  float* rpb = rp + ((size_t)lb * 16 + jt) * kN + i0 + m_off;
#pragma unroll
  for (int qa = 0; qa < 8; qa++) {
    const int i = i0 + m_off + 16 * qa + quad * 4;
    float rs[4] = {0.f, 0.f, 0.f, 0.f};
#pragma unroll
    for (int qb = 0; qb < 4; qb++) {
      const int j = j0 + n_off + 16 * qb + l15;
#pragma unroll
      for (int r = 0; r < 4; r++) {
        const f16 h = (f16)(acc[qa][qb][r] * kScale);
        Sb[(size_t)(i + r) * kN + j] = h;
        rs[r] += __expf((float)h);
      }
    }
#pragma unroll
    for (int r = 0; r < 4; r++) {
      float s = rs[r];
      s += __shfl_xor(s, 1);
      s += __shfl_xor(s, 2);
      s += __shfl_xor(s, 4);
      s += __shfl_xor(s, 8);
      if (l15 == 0) rpb[16 * qa + 4 * quad + r] = s;
    }
  }
}

// ---- K3: u[lb,i] = -log(n) - log(sum of 16 row partials) -------------------
__global__ __launch_bounds__(256) void k_u(
    const float* __restrict__ rp, float* __restrict__ u) {
  const int lb = blockIdx.y;
  const int i = blockIdx.x * 256 + threadIdx.x;
  const float* r = rp + (size_t)lb * 16 * kN + i;
  float s = 0.f;
#pragma unroll
  for (int t = 0; t < 16; t++) s += r[(size_t)t * kN];
  u[lb * kN + i] = kLogMarg - __logf(s);
}

// ---- K4: E16 = f16(2^14*exp(S16+u_i)); column partial sums of exp ----------
__global__ __launch_bounds__(256) void k_cs(
    const f16* __restrict__ S16, const float* __restrict__ u,
    float* __restrict__ cp, f16* __restrict__ E16) {
  const int lb = blockIdx.z;
  const int seg = blockIdx.y;
  const int j = blockIdx.x * 256 + threadIdx.x;
  const f16* Sb = S16 + (size_t)lb * kN * kN + j;
  f16* Eb = E16 + (size_t)lb * kN * kN + j;
  const float* ub = u + lb * kN + seg * 64;
  const size_t rbase = (size_t)(seg * 64) * kN;
  float s = 0.f;
#pragma unroll 4
  for (int r = 0; r < 64; r++) {
    const float eS = __expf((float)Sb[rbase + (size_t)r * kN] + ub[r]);
    s += eS;
    Eb[rbase + (size_t)r * kN] = (f16)(eS * kPScale);
  }
  cp[((size_t)lb * 16 + seg) * kN + j] = s;
}

// ---- K5: aT[c,j] = f16(xfT[c,j] * ev_j), ev_j = (1/n)/colsum_j -------------
// (ev folded into the A operand of gemm_o so gemm_o is pure gload_lds.)
__global__ __launch_bounds__(256) void k_va(
    const float* __restrict__ cp, const f16* __restrict__ xfT,
    f16* __restrict__ aT) {
  const int lb = blockIdx.z;
  const int j = blockIdx.x * 256 + threadIdx.x;
  const int c0 = blockIdx.y * 128;
  const float* cpb = cp + (size_t)lb * 16 * kN + j;
  float s = 0.f;
#pragma unroll
  for (int r = 0; r < 16; r++) s += cpb[(size_t)r * kN];
  const float evj = kMarg / s;
  const f16* src = xfT + (size_t)lb * kD * kN + (size_t)c0 * kN + j;
  f16* dst = aT + (size_t)lb * kD * kN + (size_t)c0 * kN + j;
#pragma unroll 8
  for (int c = 0; c < 128; c++)
    dst[(size_t)c * kN] = (f16)((float)src[(size_t)c * kN] * evj);
}

// ---- K6: out[b,c,i] = (1/2^14) * sum_j aT[c,j] * E16[i,j] (f16 MFMA) -------
// Same phase-split counted-vmcnt schedule as k_gemm_s; K=1024 (16 tiles),
// row stride 2048 B, both operands via gload_lds.
__global__ __launch_bounds__(512) void k_gemm_o(
    const f16* __restrict__ aT, const f16* __restrict__ E16,
    float* __restrict__ out, int b0) {
  __shared__ char sm[131072];
  const int nwg = (int)(gridDim.x * gridDim.y * gridDim.z);  // 8*g, %8==0
  const int lin = (int)(blockIdx.x +
                        gridDim.x * (blockIdx.y + gridDim.y * blockIdx.z));
  const int wid = (lin & 7) * (nwg >> 3) + (lin >> 3);
  const int bx = wid & 3, by = (wid >> 2) & 1, bz = wid >> 3;

  const int lb = bz;
  const int i0 = bx * 256, c0 = by * 256;
  const char* Ab = (const char*)(aT + (size_t)lb * kD * kN);   // rows c
  const char* Bb = (const char*)(E16 + (size_t)lb * kN * kN);  // rows i
  const int t = threadIdx.x;
  const int w = t >> 6, lane = t & 63;
  const int wm = w >> 2, wn = w & 3;
  const int m_off = wm * 128, n_off = wn * 64;
  const int quad = lane >> 4, l15 = lane & 15;
  const int swz = (l15 & 7) << 4;

  int srcA[4], srcB[4], ldsw[4];
#pragma unroll
  for (int p = 0; p < 4; p++) {
    const int off = p * 8192 + t * 16;
    const int r = off >> 7;
    const int cb = (off & 127) ^ ((r & 7) << 4);
    srcA[p] = (c0 + r) * (kN * 2) + cb;  // row stride 2048 B
    srcB[p] = (i0 + r) * (kN * 2) + cb;
    ldsw[p] = p * 8192 + w * 1024;
  }

  // prologue: stage K-tile 0 into buf0
#pragma unroll
  for (int p = 0; p < 4; p++) gload16(Ab + srcA[p], sm + ldsw[p]);
#pragma unroll
  for (int p = 0; p < 4; p++) gload16(Bb + srcB[p], sm + 32768 + ldsw[p]);

  f32x4 acc[8][4];
#pragma unroll
  for (int a = 0; a < 8; a++)
#pragma unroll
    for (int b = 0; b < 4; b++) acc[a][b] = (f32x4){0.f, 0.f, 0.f, 0.f};

#pragma unroll
  for (int tt = 0; tt < 16; tt++) {
    const int cur = tt & 1, nxt = cur ^ 1;
    const char* rA = sm + (cur << 16);
    const char* rB = rA + 32768;
    char* wA = sm + (nxt << 16);
    char* wB = wA + 32768;
    const int k0b = (tt + 1) * 128;
    f16x8 bf[4][2];
#pragma unroll
    for (int q = 0; q < 4; q++) {
      if (q == 0) {
        if (tt + 1 < 16) {
          gload16(Ab + srcA[0] + k0b, wA + ldsw[0]);
          gload16(Bb + srcB[0] + k0b, wB + ldsw[0]);
          asm volatile("s_waitcnt vmcnt(2)" ::: "memory");
        } else {
          asm volatile("s_waitcnt vmcnt(0)" ::: "memory");
        }
        __builtin_amdgcn_s_barrier();
#pragma unroll
        for (int qb = 0; qb < 4; qb++)
#pragma unroll
          for (int kk = 0; kk < 2; kk++)
            bf[qb][kk] = *(const f16x8*)(rB + (n_off + 16 * qb + l15) * 128 +
                                         ((kk * 64 + quad * 16) ^ swz));
      } else {
        if (tt + 1 < 16) {
          gload16(Ab + srcA[q] + k0b, wA + ldsw[q]);
          gload16(Bb + srcB[q] + k0b, wB + ldsw[q]);
        }
      }
      f16x8 af[2][2];
#pragma unroll
      for (int pa = 0; pa < 2; pa++)
#pragma unroll
        for (int kk = 0; kk < 2; kk++)
          af[pa][kk] = *(const f16x8*)(rA + (m_off + 16 * (2 * q + pa) + l15) * 128 +
                                       ((kk * 64 + quad * 16) ^ swz));
      __builtin_amdgcn_s_barrier();
      __builtin_amdgcn_s_setprio(1);
#pragma unroll
      for (int pa = 0; pa < 2; pa++)
#pragma unroll
        for (int qb = 0; qb < 4; qb++)
#pragma unroll
          for (int kk = 0; kk < 2; kk++)
            acc[2 * q + pa][qb] = __builtin_amdgcn_mfma_f32_16x16x32_f16(
                af[pa][kk], bf[qb][kk], acc[2 * q + pa][qb], 0, 0, 0);
      __builtin_amdgcn_s_setprio(0);
    }
    __builtin_amdgcn_s_barrier();
  }

  float* ob = out + ((size_t)(b0 + lb) * kD) * kN;
#pragma unroll
  for (int qa = 0; qa < 8; qa++) {
    const int c = c0 + m_off + 16 * qa + quad * 4;
#pragma unroll
    for (int qb = 0; qb < 4; qb++) {
      const int i = i0 + n_off + 16 * qb + l15;
#pragma unroll
      for (int r = 0; r < 4; r++)
        ob[(size_t)(c + r) * kN + i] = acc[qa][qb][r] * kPInv;
    }
  }
}

extern "C" void kernel_launch(void* const* d_in, const int* in_sizes, int n_in,
                              void* d_out, int out_size, void* d_ws, size_t ws_size,
                              hipStream_t stream) {
  const float* x = (const float*)d_in[0];
  const float* re = (const float*)d_in[1];
  const float* ce = (const float*)d_in[2];
  float* out = (float*)d_out;

  // ws per batch: S16 2MB + xf 1MB + xfT 1MB + E16 2MB + aT 1MB
  //             + u 4KB + rp 64KB + cp 64KB = ~7.1 MB. 32x = 238MB < 256MiB.
  char* wsb = (char*)d_ws;
  const size_t perb = 2097152ull + 1048576 + 1048576 + 2097152 + 1048576 +
                      4096 + 65536 + 65536;
  int G = (int)(ws_size / perb);
  if (G >= 32) G = 32;
  else if (G >= 16) G = 16;
  else if (G >= 8) G = 8;
  else if (G >= 4) G = 4;
  else if (G < 1) G = 1;
  f16* S16 = (f16*)wsb;
  f16* xf = (f16*)(wsb + (size_t)G * 2097152);
  f16* xfT = (f16*)((char*)xf + (size_t)G * 1048576);
  f16* E16 = (f16*)((char*)xfT + (size_t)G * 1048576);
  f16* aT = (f16*)((char*)E16 + (size_t)G * 2097152);
  float* u = (float*)((char*)aT + (size_t)G * 1048576);
  float* rp = u + (size_t)G * kN;              // [G][16][kN]
  float* cp = rp + (size_t)G * 16 * kN;        // [G][16][kN]

  for (int b0 = 0; b0 < kB; b0 += G) {
    const int g = (kB - b0 < G) ? (kB - b0) : G;
    k_prep<<<dim3(16, 8, g), 256, 0, stream>>>(x, re, ce, xf, xfT, b0);
    k_gemm_s<<<dim3(4, 4, g), 512, 0, stream>>>(xf, S16, rp);
    k_u<<<dim3(4, g), 256, 0, stream>>>(rp, u);
    k_cs<<<dim3(4, 16, g), 256, 0, stream>>>(S16, u, cp, E16);
    k_va<<<dim3(4, 4, g), 256, 0, stream>>>(cp, xfT, aT);
    k_gemm_o<<<dim3(4, 2, g), 512, 0, stream>>>(aT, E16, out, b0);
  }
}

// Round 5
// 239.001 us; speedup vs baseline: 1.0753x; 1.0269x over previous
//
#include <hip/hip_runtime.h>
#include <hip/hip_fp16.h>
#include <math.h>

typedef _Float16 f16;
typedef _Float16 f16x8 __attribute__((ext_vector_type(8)));
typedef _Float16 f16x4 __attribute__((ext_vector_type(4)));
typedef float f32x4 __attribute__((ext_vector_type(4)));

namespace {
constexpr int kB = 32, kD = 512, kN = 1024, kF = 256;
constexpr float kScale = 0.04419417382415922f;   // 1/sqrt(512)
constexpr float kLogMarg = -6.931471805599453f;  // -log(1024)
constexpr float kMarg = 1.f / 1024.f;            // 1/n
constexpr float kPScale = 16384.f;               // 2^14: lift exp into f16 range
constexpr float kPInv = 1.f / 16384.f;
}

// global -> LDS direct DMA, 16B per lane. LDS dest is wave-uniform base +
// lane*16 (hardware); global src is per-lane.
__device__ __forceinline__ void gload16(const void* g, void* l) {
  __builtin_amdgcn_global_load_lds(
      (const __attribute__((address_space(1))) void*)g,
      (__attribute__((address_space(3))) void*)l, 16, 0, 0);
}

// ---- K1: val = x[b,c,i] + pos(c,i); emit xfT[lb,c,i] and xf[lb,i,c] (f16) --
__global__ __launch_bounds__(256) void k_prep(
    const float* __restrict__ x, const float* __restrict__ re,
    const float* __restrict__ ce, f16* __restrict__ xf,
    f16* __restrict__ xfT, int b0) {
  __shared__ f16 T[64][68];
  const int lb = blockIdx.z;
  const int i0 = blockIdx.x * 64, c0 = blockIdx.y * 64;
  const int t = threadIdx.x;
  const int il = (t & 15) * 4;  // 0..60
  const int cl = t >> 4;        // 0..15
  const size_t xbase = ((size_t)(b0 + lb) * kD) * kN;
#pragma unroll
  for (int p = 0; p < 4; p++) {
    const int c = c0 + cl + 16 * p;
    const int i = i0 + il;
    const float4 xv = *(const float4*)(x + xbase + (size_t)c * kN + i);
    float4 pv;
    if (c < kF) {  // wave-uniform per block (c0 multiple of 64)
      pv.x = ce[((i + 0) & 31) * kF + c];
      pv.y = ce[((i + 1) & 31) * kF + c];
      pv.z = ce[((i + 2) & 31) * kF + c];
      pv.w = ce[((i + 3) & 31) * kF + c];
    } else {
      const float r = re[(i >> 5) * kF + (c - kF)];
      pv.x = r; pv.y = r; pv.z = r; pv.w = r;
    }
    const f16 h0 = (f16)(xv.x + pv.x), h1 = (f16)(xv.y + pv.y);
    const f16 h2 = (f16)(xv.z + pv.z), h3 = (f16)(xv.w + pv.w);
    f16* dT = xfT + ((size_t)lb * kD + c) * kN + i;
    *(f16x4*)dT = (f16x4){h0, h1, h2, h3};
    T[cl + 16 * p][il + 0] = h0; T[cl + 16 * p][il + 1] = h1;
    T[cl + 16 * p][il + 2] = h2; T[cl + 16 * p][il + 3] = h3;
  }
  __syncthreads();
#pragma unroll
  for (int p = 0; p < 4; p++) {
    const int ir = cl + 16 * p;  // local i
    const int cc = il;           // local c
    const f16 h0 = T[cc + 0][ir], h1 = T[cc + 1][ir];
    const f16 h2 = T[cc + 2][ir], h3 = T[cc + 3][ir];
    f16* dF = xf + ((size_t)lb * kN + i0 + ir) * kD + c0 + cc;
    *(f16x4*)dF = (f16x4){h0, h1, h2, h3};
  }
}

// Per-phase fragment read + MFMA cluster (shared by both GEMMs).
#define AF_READ(q)                                                          \
  _Pragma("unroll")                                                         \
  for (int pa = 0; pa < 2; pa++)                                            \
    _Pragma("unroll")                                                       \
    for (int kk = 0; kk < 2; kk++)                                          \
      af[pa][kk] = *(const f16x8*)(bA + (m_off + 32*(q) + 16*pa + l15)*128  \
                                   + ((kk*64 + quad*16) ^ swz));

#define MFMA_PH(q)                                                          \
  __builtin_amdgcn_s_setprio(1);                                            \
  _Pragma("unroll")                                                         \
  for (int pa = 0; pa < 2; pa++)                                            \
    _Pragma("unroll")                                                       \
    for (int qb = 0; qb < 4; qb++)                                          \
      _Pragma("unroll")                                                     \
      for (int kk = 0; kk < 2; kk++)                                        \
        acc[2*(q)+pa][qb] = __builtin_amdgcn_mfma_f32_16x16x32_f16(         \
            af[pa][kk], bf[qb][kk], acc[2*(q)+pa][qb], 0, 0, 0);            \
  __builtin_amdgcn_s_setprio(0);

// Split-group deep-lead K-loop, 4 phases/K-tile (see theory):
//   issue A{0,2}(t+1)@P1, A{1,3}(t+1)+B(t+2)@P3; vmcnt(6) after P1 and P3.
//   B region of tile t is dead after P0 (B fully register-loaded), so B
//   rotates 2 tiles ahead into the same slot (4-phase lead); A keeps the
//   2-buffer rotation (2-phase lead). LDS: A[2] at 0/32K, B[2] at 64K/96K.
#define GEMM_KLOOP(NT, Abase, Bbase, sA, sB)                                \
  _Pragma("unroll")                                                         \
  for (int tt = 0; tt < (NT); tt++) {                                       \
    const int cur = tt & 1, nxt = cur ^ 1;                                  \
    const char* bA = sm + cur * 32768;                                      \
    const char* bB = sm + 65536 + cur * 32768;                              \
    char* wA = sm + nxt * 32768;                                            \
    char* wB = sm + 65536 + cur * 32768;                                    \
    const int kA = (tt + 1) * 128, kBB = (tt + 2) * 128;                    \
    f16x8 bf[4][2], af[2][2];                                               \
    /* P0: all B + A-phase0 fragments; drain; WAR-proof barrier */          \
    _Pragma("unroll")                                                       \
    for (int qb = 0; qb < 4; qb++)                                          \
      _Pragma("unroll")                                                     \
      for (int kk = 0; kk < 2; kk++)                                        \
        bf[qb][kk] = *(const f16x8*)(bB + (n_off + 16*qb + l15)*128         \
                                     + ((kk*64 + quad*16) ^ swz));          \
    AF_READ(0)                                                              \
    asm volatile("s_waitcnt lgkmcnt(0)" ::: "memory");                      \
    __builtin_amdgcn_sched_barrier(0);                                      \
    __builtin_amdgcn_s_barrier();                                           \
    MFMA_PH(0)                                                              \
    /* P1: issue A chunks 0,2 of t+1 */                                     \
    if (tt + 1 < (NT)) {                                                    \
      gload16((Abase) + (sA)[0] + kA, wA + ldsw[0]);                        \
      gload16((Abase) + (sA)[2] + kA, wA + ldsw[2]);                        \
    }                                                                       \
    AF_READ(1)                                                              \
    __builtin_amdgcn_s_barrier();                                           \
    MFMA_PH(1)                                                              \
    if (tt == (NT) - 1) { asm volatile("s_waitcnt vmcnt(0)" ::: "memory"); }\
    else                { asm volatile("s_waitcnt vmcnt(6)" ::: "memory"); }\
    __builtin_amdgcn_s_barrier();                                           \
    __builtin_amdgcn_sched_barrier(0);                                      \
    /* P2 */                                                                \
    AF_READ(2)                                                              \
    __builtin_amdgcn_s_barrier();                                           \
    MFMA_PH(2)                                                              \
    /* P3: issue A chunks 1,3 of t+1 and all B of t+2 */                    \
    if (tt + 1 < (NT)) {                                                    \
      gload16((Abase) + (sA)[1] + kA, wA + ldsw[1]);                        \
      gload16((Abase) + (sA)[3] + kA, wA + ldsw[3]);                        \
    }                                                                       \
    if (tt + 2 < (NT)) {                                                    \
      _Pragma("unroll")                                                     \
      for (int p = 0; p < 4; p++)                                           \
        gload16((Bbase) + (sB)[p] + kBB, wB + ldsw[p]);                     \
    }                                                                       \
    AF_READ(3)                                                              \
    __builtin_amdgcn_s_barrier();                                           \
    MFMA_PH(3)                                                              \
    if (tt + 2 < (NT))      { asm volatile("s_waitcnt vmcnt(6)" ::: "memory"); } \
    else if (tt + 1 < (NT)) { asm volatile("s_waitcnt vmcnt(2)" ::: "memory"); } \
    __builtin_amdgcn_s_barrier();                                           \
    __builtin_amdgcn_sched_barrier(0);                                      \
  }

// Prologue: B(0) x4, A{0,2}(0), A{1,3}(0), B(1) x4 -> vmcnt(6) proves
// B(0)+A{0,2}(0); A{1,3}(0) and B(1) stay in flight (uniform with loop).
#define GEMM_PROLOGUE(Abase, Bbase, sA, sB)                                 \
  _Pragma("unroll")                                                         \
  for (int p = 0; p < 4; p++) gload16((Bbase) + (sB)[p], sm + 65536 + ldsw[p]); \
  gload16((Abase) + (sA)[0], sm + ldsw[0]);                                 \
  gload16((Abase) + (sA)[2], sm + ldsw[2]);                                 \
  gload16((Abase) + (sA)[1], sm + ldsw[1]);                                 \
  gload16((Abase) + (sA)[3], sm + ldsw[3]);                                 \
  _Pragma("unroll")                                                         \
  for (int p = 0; p < 4; p++)                                               \
    gload16((Bbase) + (sB)[p] + 128, sm + 65536 + 32768 + ldsw[p]);         \
  f32x4 acc[8][4];                                                          \
  _Pragma("unroll")                                                         \
  for (int a = 0; a < 8; a++)                                               \
    _Pragma("unroll")                                                       \
    for (int b = 0; b < 4; b++) acc[a][b] = (f32x4){0.f, 0.f, 0.f, 0.f};    \
  asm volatile("s_waitcnt vmcnt(6)" ::: "memory");                          \
  __builtin_amdgcn_s_barrier();                                             \
  __builtin_amdgcn_sched_barrier(0);

// ---- K2: S16 = f16(kScale * xf @ xf^T) -------------------------------------
// 256x256 tile, 8 waves (2Mx4N), per-wave 128x64, BK=64. T1 XCD swizzle,
// T2 XOR swizzle (pre-swizzled gload source + swizzled ds_read), T5 setprio.
__global__ __launch_bounds__(512) void k_gemm_s(
    const f16* __restrict__ xf, f16* __restrict__ S16,
    float* __restrict__ rp) {
  __shared__ char sm[131072];  // A0|A1|B0|B1, 32KB each
  const int nwg = (int)(gridDim.x * gridDim.y * gridDim.z);  // 16*g, %8==0
  const int lin = (int)(blockIdx.x +
                        gridDim.x * (blockIdx.y + gridDim.y * blockIdx.z));
  const int wid = (lin & 7) * (nwg >> 3) + (lin >> 3);
  const int bx = wid & 3, by = (wid >> 2) & 3, bz = wid >> 4;

  const int lb = bz;
  const int i0 = by * 256, j0 = bx * 256;
  const char* base = (const char*)(xf + (size_t)lb * kN * kD);
  const int t = threadIdx.x;  // 0..511
  const int w = t >> 6, lane = t & 63;
  const int wm = w >> 2, wn = w & 3;            // wave grid 2M x 4N
  const int m_off = wm * 128, n_off = wn * 64;  // per-wave 128x64
  const int quad = lane >> 4, l15 = lane & 15;
  const int swz = (l15 & 7) << 4;

  // staging: 32KB operand tile = 4 chunks x (512 thr x 16B); chunk p covers
  // rows 64p..64p+63.
  int srcA[4], srcB[4], ldsw[4];
#pragma unroll
  for (int p = 0; p < 4; p++) {
    const int off = p * 8192 + t * 16;
    const int r = off >> 7;                       // tile row 0..255
    const int cb = (off & 127) ^ ((r & 7) << 4);  // inverse-swizzled src col
    srcA[p] = (i0 + r) * (kD * 2) + cb;           // row stride 1024 B
    srcB[p] = (j0 + r) * (kD * 2) + cb;
    ldsw[p] = p * 8192 + w * 1024;                // wave-uniform LDS base
  }

  GEMM_PROLOGUE(base, base, srcA, srcB)
  GEMM_KLOOP(8, base, base, srcA, srcB)

  f16* Sb = S16 + (size_t)lb * kN * kN;
  const int jt = bx * 4 + wn;  // 0..15: 64-wide j segment index
  float* rpb = rp + ((size_t)lb * 16 + jt) * kN + i0 + m_off;
#pragma unroll
  for (int qa = 0; qa < 8; qa++) {
    const int i = i0 + m_off + 16 * qa + quad * 4;
    float rs[4] = {0.f, 0.f, 0.f, 0.f};
#pragma unroll
    for (int qb = 0; qb < 4; qb++) {
      const int j = j0 + n_off + 16 * qb + l15;
#pragma unroll
      for (int r = 0; r < 4; r++) {
        const f16 h = (f16)(acc[qa][qb][r] * kScale);
        Sb[(size_t)(i + r) * kN + j] = h;
        rs[r] += __expf((float)h);
      }
    }
#pragma unroll
    for (int r = 0; r < 4; r++) {
      float s = rs[r];
      s += __shfl_xor(s, 1);
      s += __shfl_xor(s, 2);
      s += __shfl_xor(s, 4);
      s += __shfl_xor(s, 8);
      if (l15 == 0) rpb[16 * qa + 4 * quad + r] = s;
    }
  }
}

// ---- K3: u[lb,i] = -log(n) - log(sum of 16 row partials) -------------------
__global__ __launch_bounds__(256) void k_u(
    const float* __restrict__ rp, float* __restrict__ u) {
  const int lb = blockIdx.y;
  const int i = blockIdx.x * 256 + threadIdx.x;
  const float* r = rp + (size_t)lb * 16 * kN + i;
  float s = 0.f;
#pragma unroll
  for (int t = 0; t < 16; t++) s += r[(size_t)t * kN];
  u[lb * kN + i] = kLogMarg - __logf(s);
}

// ---- K4: column partial sums of exp(S16 + u_i), 64 rows per seg ------------
__global__ __launch_bounds__(256) void k_cs(
    const f16* __restrict__ S16, const float* __restrict__ u,
    float* __restrict__ cp) {
  const int lb = blockIdx.z;
  const int seg = blockIdx.y;
  const int j = blockIdx.x * 256 + threadIdx.x;
  const f16* Sb = S16 + (size_t)lb * kN * kN + j;
  const float* ub = u + lb * kN + seg * 64;
  const size_t rbase = (size_t)(seg * 64) * kN;
  float s = 0.f;
#pragma unroll 4
  for (int r = 0; r < 64; r++)
    s += __expf((float)Sb[rbase + (size_t)r * kN] + ub[r]);
  cp[((size_t)lb * 16 + seg) * kN + j] = s;
}

// ---- K5: ev[lb,j] = exp(v_j) = (1/n) / colsum_j ----------------------------
__global__ __launch_bounds__(256) void k_v(
    const float* __restrict__ cp, float* __restrict__ ev) {
  const int lb = blockIdx.y;
  const int j = blockIdx.x * 256 + threadIdx.x;
  const float* c = cp + (size_t)lb * 16 * kN + j;
  float s = 0.f;
#pragma unroll
  for (int r = 0; r < 16; r++) s += c[(size_t)r * kN];
  ev[lb * kN + j] = kMarg / s;
}

// ---- K6: t16[i,j] = f16(2^14 * exp(S16 + u_i) * ev_j)  (= 2^14 * pi_ij) ----
__global__ __launch_bounds__(256) void k_pt(
    const f16* __restrict__ S16, const float* __restrict__ u,
    const float* __restrict__ ev, f16* __restrict__ t16) {
  const int row = blockIdx.x;  // lb*kN + i
  const float ui = u[row];
  const f16* Sr = S16 + (size_t)row * kN;
  const float* evb = ev + (size_t)(row >> 10) * kN;
  f16* Tr = t16 + (size_t)row * kN;
  const int j = threadIdx.x * 4;
  const f16x4 s = *(const f16x4*)(Sr + j);
  const float4 e = *(const float4*)(evb + j);
  f16x4 o;
  o[0] = (f16)(__expf((float)s[0] + ui) * e.x * kPScale);
  o[1] = (f16)(__expf((float)s[1] + ui) * e.y * kPScale);
  o[2] = (f16)(__expf((float)s[2] + ui) * e.z * kPScale);
  o[3] = (f16)(__expf((float)s[3] + ui) * e.w * kPScale);
  *(f16x4*)(Tr + j) = o;
}

// ---- K7: out[b,c,i] = (1/2^14) * sum_j xfT[c,j] * t16[i,j]  (f16 MFMA) -----
// Same split-group deep-lead schedule; K=1024 (16 tiles), row stride 2048 B.
__global__ __launch_bounds__(512) void k_gemm_o(
    const f16* __restrict__ xfT, const f16* __restrict__ P,
    float* __restrict__ out, int b0) {
  __shared__ char sm[131072];
  const int nwg = (int)(gridDim.x * gridDim.y * gridDim.z);  // 8*g, %8==0
  const int lin = (int)(blockIdx.x +
                        gridDim.x * (blockIdx.y + gridDim.y * blockIdx.z));
  const int wid = (lin & 7) * (nwg >> 3) + (lin >> 3);
  const int bx = wid & 3, by = (wid >> 2) & 1, bz = wid >> 3;

  const int lb = bz;
  const int i0 = bx * 256, c0 = by * 256;
  const char* Ab = (const char*)(xfT + (size_t)lb * kD * kN);  // rows c
  const char* Bb = (const char*)(P + (size_t)lb * kN * kN);    // rows i
  const int t = threadIdx.x;
  const int w = t >> 6, lane = t & 63;
  const int wm = w >> 2, wn = w & 3;
  const int m_off = wm * 128, n_off = wn * 64;
  const int quad = lane >> 4, l15 = lane & 15;
  const int swz = (l15 & 7) << 4;

  int srcA[4], srcB[4], ldsw[4];
#pragma unroll
  for (int p = 0; p < 4; p++) {
    const int off = p * 8192 + t * 16;
    const int r = off >> 7;
    const int cb = (off & 127) ^ ((r & 7) << 4);
    srcA[p] = (c0 + r) * (kN * 2) + cb;  // row stride 2048 B
    srcB[p] = (i0 + r) * (kN * 2) + cb;
    ldsw[p] = p * 8192 + w * 1024;
  }

  GEMM_PROLOGUE(Ab, Bb, srcA, srcB)
  GEMM_KLOOP(16, Ab, Bb, srcA, srcB)

  float* ob = out + ((size_t)(b0 + lb) * kD) * kN;
#pragma unroll
  for (int qa = 0; qa < 8; qa++) {
    const int c = c0 + m_off + 16 * qa + quad * 4;
#pragma unroll
    for (int qb = 0; qb < 4; qb++) {
      const int i = i0 + n_off + 16 * qb + l15;
#pragma unroll
      for (int r = 0; r < 4; r++)
        ob[(size_t)(c + r) * kN + i] = acc[qa][qb][r] * kPInv;
    }
  }
}

extern "C" void kernel_launch(void* const* d_in, const int* in_sizes, int n_in,
                              void* d_out, int out_size, void* d_ws, size_t ws_size,
                              hipStream_t stream) {
  const float* x = (const float*)d_in[0];
  const float* re = (const float*)d_in[1];
  const float* ce = (const float*)d_in[2];
  float* out = (float*)d_out;

  // ws per batch: S16 2MB + xf 1MB + xfT 1MB + t16 2MB + u 4KB + ev 4KB
  //             + rp 64KB + cp 64KB = ~6.13 MB. ws=256MiB -> G=32, ONE chunk.
  char* wsb = (char*)d_ws;
  const size_t perb = 2097152ull + 1048576 + 1048576 + 2097152 +
                      4096 + 4096 + 65536 + 65536;
  int G = (int)(ws_size / perb);
  if (G >= 32) G = 32;
  else if (G >= 16) G = 16;
  else if (G >= 8) G = 8;
  else if (G >= 4) G = 4;
  else if (G < 1) G = 1;
  f16* S16 = (f16*)wsb;
  f16* xf = (f16*)(wsb + (size_t)G * 2097152);
  f16* xfT = (f16*)((char*)xf + (size_t)G * 1048576);
  f16* t16 = (f16*)((char*)xfT + (size_t)G * 1048576);
  float* u = (float*)((char*)t16 + (size_t)G * 2097152);
  float* ev = u + (size_t)G * kN;
  float* rp = ev + (size_t)G * kN;            // [G][16][kN]
  float* cp = rp + (size_t)G * 16 * kN;       // [G][16][kN]

  for (int b0 = 0; b0 < kB; b0 += G) {
    const int g = (kB - b0 < G) ? (kB - b0) : G;
    k_prep<<<dim3(16, 8, g), 256, 0, stream>>>(x, re, ce, xf, xfT, b0);
    k_gemm_s<<<dim3(4, 4, g), 512, 0, stream>>>(xf, S16, rp);
    k_u<<<dim3(4, g), 256, 0, stream>>>(rp, u);
    k_cs<<<dim3(4, 16, g), 256, 0, stream>>>(S16, u, cp);
    k_v<<<dim3(4, g), 256, 0, stream>>>(cp, ev);
    k_pt<<<g * kN, 256, 0, stream>>>(S16, u, ev, t16);
    k_gemm_o<<<dim3(4, 2, g), 512, 0, stream>>>(xfT, t16, out, b0);
  }
}